// Round 12
// baseline (383.985 us; speedup 1.0000x reference)
//
#include <hip/hip_runtime.h>
#include <math.h>

#define NN 20000
#define EE 320000
#define GG 64
#define HH 8
#define EPSV 1e-5f

static inline unsigned int gridFor(long n, int b){ return (unsigned int)((n + b - 1)/b); }

typedef __attribute__((ext_vector_type(8))) short short8;
typedef __attribute__((ext_vector_type(4))) float f32x4;
typedef unsigned short ushort_t;

// ---------------- bf16 helpers ----------------
__device__ __forceinline__ float asf(unsigned int u){
    union{unsigned int i; float f;} c; c.i = u; return c.f;
}
__device__ __forceinline__ ushort_t f2bf(float x){   // RNE
    unsigned u = __float_as_uint(x);
    unsigned r = u + 0x7FFFu + ((u >> 16) & 1u);
    return (ushort_t)(r >> 16);
}
__device__ __forceinline__ void split_bf16(float x, short& hi, short& lo){
    unsigned u = __float_as_uint(x);
    unsigned r = u + 0x7FFFu + ((u >> 16) & 1u);
    hi = (short)(r >> 16);
    float hf = asf(((unsigned)(unsigned short)hi) << 16);
    float res = x - hf;
    unsigned u2 = __float_as_uint(res);
    unsigned r2 = u2 + 0x7FFFu + ((u2 >> 16) & 1u);
    lo = (short)(r2 >> 16);
}

// ---------------- weight prep (all 3 layers) + cursor zeroing ----------------
__device__ __forceinline__ void wprep_one(const float* Wl, const float* Wr,
                                          ushort_t* Whi, ushort_t* Wlo,
                                          int K, int Kp, int HC, int t){
    int octs = Kp >> 3;
    int n = t / octs, ko = t - n*octs;
    int kb = ko*8;
    const float* W = (n < HC) ? (Wl + n) : (Wr + (n - HC));
    short hi[8], lo[8];
    #pragma unroll
    for (int j = 0; j < 8; ++j){
        int k = kb + j;
        float v = (k < K) ? W[(long)k*HC] : 0.f;
        split_bf16(v, hi[j], lo[j]);
    }
    long base = (((long)(n>>4)*(Kp>>5) + (kb>>5))*64 + (n&15) + 16*((kb>>3)&3))*8;
    *(short8*)&Whi[base] = *(short8*)hi;
    *(short8*)&Wlo[base] = *(short8*)lo;
}

#define WP1 2048
#define WP2 8192
#define WP3 2048

__global__ void k_wprep_all(const float* __restrict__ W1l, const float* __restrict__ W1r,
                            const float* __restrict__ W2l, const float* __restrict__ W2r,
                            const float* __restrict__ W3l, const float* __restrict__ W3r,
                            ushort_t* __restrict__ W1hi, ushort_t* __restrict__ W1lo,
                            ushort_t* __restrict__ W2hi, ushort_t* __restrict__ W2lo,
                            ushort_t* __restrict__ W3hi, ushort_t* __restrict__ W3lo,
                            int* __restrict__ cursor){
    int t = blockIdx.x*blockDim.x + threadIdx.x;
    if (t < NN) cursor[t] = 0;
    if (t < WP1) wprep_one(W1l, W1r, W1hi, W1lo, 19, 32, 256, t);
    else if (t < WP1+WP2) wprep_one(W2l, W2r, W2hi, W2lo, 256, 256, 128, t-WP1);
    else if (t < WP1+WP2+WP3) wprep_one(W3l, W3r, W3hi, W3lo, 128, 128, 64, t-WP1-WP2);
}

// ---------------- degree count + graph bounds + gn-partial zeroing ----------------
__global__ void k_degbounds(const int* __restrict__ edst, int* __restrict__ deg,
                            const int* __restrict__ batch,
                            int* __restrict__ gstart, int* __restrict__ gend,
                            float* __restrict__ gz){
    int e = blockIdx.x*blockDim.x + threadIdx.x;
    if (e < EE) atomicAdd(&deg[edst[e]], 1);
    if (e < NN){
        int b = batch[e];
        if (e == 0 || batch[e-1] != b) gstart[b] = e;
        if (e == NN-1 || batch[e+1] != b) gend[b] = e+1;
    }
    if (e < 2*GG*256) gz[e] = 0.f;
}

// ---------------- exclusive scan, int4-vectorized (NN = 1000*20 exactly) ----------------
__global__ void k_scan(int* __restrict__ deg, int* __restrict__ indptr){
    __shared__ int partial[1024];
    int t = threadIdx.x;
    int vals[20];
    int sum = 0;
    if (t < 1000){
        int4 buf[5];
        const int4* p = (const int4*)(deg + t*20);   // 80t bytes: 16B-aligned
        #pragma unroll
        for (int i = 0; i < 5; ++i) buf[i] = p[i];
        const int* bv = (const int*)buf;
        #pragma unroll
        for (int i = 0; i < 20; ++i){ vals[i] = sum; sum += bv[i]; }
        int4 z = make_int4(0,0,0,0);
        int4* pz = (int4*)(deg + t*20);              // re-zero cursor for scatter
        #pragma unroll
        for (int i = 0; i < 5; ++i) pz[i] = z;
    }
    partial[t] = sum;
    __syncthreads();
    for (int off = 1; off < 1024; off <<= 1){
        int v = (t >= off) ? partial[t-off] : 0;
        __syncthreads();
        partial[t] += v;
        __syncthreads();
    }
    int prefix = (t > 0) ? partial[t-1] : 0;
    if (t < 1000){
        int out[20];
        #pragma unroll
        for (int i = 0; i < 20; ++i) out[i] = prefix + vals[i];
        int4* q = (int4*)(indptr + t*20);
        #pragma unroll
        for (int i = 0; i < 5; ++i) q[i] = ((const int4*)out)[i];
    }
    if (t == 1023) indptr[NN] = prefix;   // threads 1000..1022 contribute 0
}

// ---------------- bf16-split MFMA dual linear body (shared by both gemm kernels) ----------------
template<bool NORM>
__device__ __forceinline__ void gemm_body(
    const float* __restrict__ h,
    const ushort_t* __restrict__ Whi, const ushort_t* __restrict__ Wlo,
    const float* __restrict__ bl, const float* __restrict__ br,
    const float* __restrict__ gmu, const float* __restrict__ ginv,
    const float* __restrict__ nw, const float* __restrict__ nb,
    const int* __restrict__ batch,
    ushort_t* __restrict__ xlb, float* __restrict__ xr,
    int K, int Kp, int HC, int bm, int bn){
    __shared__ short Ahi[2][64*32], Alo[2][64*32];
    const int tid  = threadIdx.x;
    const int lane = tid & 63;
    const int wave = tid >> 6;
    const int m0   = bm * 64;
    const int n0   = bn * 128;
    const int wr   = (wave & 1) * 32;
    const int wcg  = (wave >> 1) * 64;
    const int kblocks = Kp >> 5;

    const int srow = tid >> 2;
    const int soct = tid & 3;

    f32x4 acc[2][4] = {};

    for (int kb = 0; kb < kblocks; ++kb){
        int p = kb & 1;
        int k0 = kb*32;
        {
            int gm = m0 + srow;
            int kbase = k0 + soct*8;
            float v[8];
            const float* src = h + (long)gm*K + kbase;
            if (gm < NN && kbase + 8 <= K){
                float4 t0 = *(const float4*)src;
                float4 t1 = *(const float4*)(src+4);
                v[0]=t0.x; v[1]=t0.y; v[2]=t0.z; v[3]=t0.w;
                v[4]=t1.x; v[5]=t1.y; v[6]=t1.z; v[7]=t1.w;
            } else {
                #pragma unroll
                for (int j = 0; j < 8; ++j)
                    v[j] = (gm < NN && kbase + j < K) ? src[j] : 0.f;
            }
            if (NORM && gm < NN){
                int g = batch[gm];
                const float* mu = gmu + (long)g*K;
                const float* iv = ginv + (long)g*K;
                #pragma unroll
                for (int j = 0; j < 8; ++j){
                    int c = kbase + j;
                    float t = (v[j] - mu[c]) * iv[c] * nw[c] + nb[c];
                    v[j] = fmaxf(t, 0.f);
                }
            }
            short hi[8], lo[8];
            #pragma unroll
            for (int j = 0; j < 8; ++j) split_bf16(v[j], hi[j], lo[j]);
            long off = ((long)(srow>>4)*64 + (srow&15) + 16*soct)*8;
            *(short8*)&Ahi[p][off] = *(short8*)hi;
            *(short8*)&Alo[p][off] = *(short8*)lo;
        }
        __syncthreads();

        int rb0 = wr >> 4;
        short8 ah0 = *(short8*)&Ahi[p][((rb0  )*64 + lane)*8];
        short8 ah1 = *(short8*)&Ahi[p][((rb0+1)*64 + lane)*8];
        short8 al0 = *(short8*)&Alo[p][((rb0  )*64 + lane)*8];
        short8 al1 = *(short8*)&Alo[p][((rb0+1)*64 + lane)*8];

        short8 bh[4], bl_[4];
        #pragma unroll
        for (int j = 0; j < 4; ++j){
            int n = n0 + wcg + j*16;
            long bbase = (((long)(n>>4)*kblocks + kb)*64 + lane)*8;
            bh[j]  = *(const short8*)&Whi[bbase];
            bl_[j] = *(const short8*)&Wlo[bbase];
        }

        #pragma unroll
        for (int j = 0; j < 4; ++j){
            acc[0][j] = __builtin_amdgcn_mfma_f32_16x16x32_bf16(al0, bh[j],  acc[0][j], 0,0,0);
            acc[0][j] = __builtin_amdgcn_mfma_f32_16x16x32_bf16(ah0, bl_[j], acc[0][j], 0,0,0);
            acc[0][j] = __builtin_amdgcn_mfma_f32_16x16x32_bf16(ah0, bh[j],  acc[0][j], 0,0,0);
            acc[1][j] = __builtin_amdgcn_mfma_f32_16x16x32_bf16(al1, bh[j],  acc[1][j], 0,0,0);
            acc[1][j] = __builtin_amdgcn_mfma_f32_16x16x32_bf16(ah1, bl_[j], acc[1][j], 0,0,0);
            acc[1][j] = __builtin_amdgcn_mfma_f32_16x16x32_bf16(ah1, bh[j],  acc[1][j], 0,0,0);
        }
    }

    #pragma unroll
    for (int i = 0; i < 2; ++i){
        int row0 = m0 + wr + i*16 + (lane >> 4)*4;
        #pragma unroll
        for (int j = 0; j < 4; ++j){
            int n = n0 + wcg + j*16 + (lane & 15);
            float bb = (n < HC) ? bl[n] : br[n - HC];
            #pragma unroll
            for (int r = 0; r < 4; ++r){
                int gm = row0 + r;
                if (gm >= NN) continue;
                float v = acc[i][j][r] + bb;
                if (n < HC) xlb[(long)gm*HC + n] = f2bf(v);
                else        xr[(long)gm*HC + (n - HC)] = v;
            }
        }
    }
}

template<bool NORM>
__global__ __launch_bounds__(256)
void k_gemm_mfma(const float* __restrict__ h,
                 const ushort_t* __restrict__ Whi, const ushort_t* __restrict__ Wlo,
                 const float* __restrict__ bl, const float* __restrict__ br,
                 const float* __restrict__ gmu, const float* __restrict__ ginv,
                 const float* __restrict__ nw, const float* __restrict__ nb,
                 const int* __restrict__ batch,
                 ushort_t* __restrict__ xlb, float* __restrict__ xr,
                 int K, int Kp, int HC){
    gemm_body<NORM>(h, Whi, Wlo, bl, br, gmu, ginv, nw, nb, batch, xlb, xr,
                    K, Kp, HC, blockIdx.x, blockIdx.y);
}

// gemm1 + scatter in one dispatch (independent work, concurrent pipes)
__global__ __launch_bounds__(256)
void k_gemm1_scatter(const float* __restrict__ x,
                     const ushort_t* __restrict__ Whi, const ushort_t* __restrict__ Wlo,
                     const float* __restrict__ bl, const float* __restrict__ br,
                     ushort_t* __restrict__ xlb, float* __restrict__ xr,
                     const int* __restrict__ esrc, const int* __restrict__ edst,
                     const int* __restrict__ indptr, int* __restrict__ cursor,
                     int* __restrict__ srclist, int nGemm, int mb){
    if ((int)blockIdx.x < nGemm){
        gemm_body<false>(x, Whi, Wlo, bl, br, nullptr, nullptr, nullptr, nullptr,
                         nullptr, xlb, xr, 19, 32, 256, blockIdx.x % mb, blockIdx.x / mb);
    } else {
        int e = (blockIdx.x - nGemm)*256 + threadIdx.x;
        if (e < EE){
            int d = edst[e];
            int pos = atomicAdd(&cursor[d], 1);
            srclist[indptr[d] + pos] = esrc[e];
        }
    }
}

// ---------------- head-sliced GATv2: 64-channel slice per pass (L2-resident gather) ----------------
__device__ __forceinline__ float lrelu(float z){ return z > 0.f ? z : 0.2f*z; }

template<int C>
__device__ __forceinline__ float redC(float v){
    #pragma unroll
    for (int m = 1; m < C; m <<= 1) v += __shfl_xor(v, m);
    return v;
}
__device__ __forceinline__ float bfld(const ushort_t* p){
    return asf(((unsigned)*p) << 16);
}

// grid (NN/4, HC/64); wave per node per slice; C = channels/head (32 or 16)
template<int C>
__global__ __launch_bounds__(256)
void k_gat_s(const int* __restrict__ indptr, const int* __restrict__ srclist,
             const ushort_t* __restrict__ xlb, const float* __restrict__ xr,
             const float* __restrict__ att, const float* __restrict__ bias,
             float* __restrict__ val, int HC){
    const int lane = threadIdx.x & 63;
    const int d = blockIdx.x*4 + (threadIdx.x >> 6);
    const int co = blockIdx.y*64 + lane;
    const long rowd = (long)d*HC + co;

    const float xrd = xr[rowd];
    const float at  = att[co];
    float xls = bfld(xlb + rowd);
    float m0 = redC<C>(lrelu(xls + xrd) * at);
    float l = 1.f, o = xls;

    int j = indptr[d], end = indptr[d+1];   // wave-uniform
    for (; j + 8 <= end; j += 8){
        int s0 = srclist[j+0], s1 = srclist[j+1], s2 = srclist[j+2], s3 = srclist[j+3];
        int s4 = srclist[j+4], s5 = srclist[j+5], s6 = srclist[j+6], s7 = srclist[j+7];
        float x0 = bfld(xlb + (long)s0*HC + co);
        float x1 = bfld(xlb + (long)s1*HC + co);
        float x2 = bfld(xlb + (long)s2*HC + co);
        float x3 = bfld(xlb + (long)s3*HC + co);
        float x4 = bfld(xlb + (long)s4*HC + co);
        float x5 = bfld(xlb + (long)s5*HC + co);
        float x6 = bfld(xlb + (long)s6*HC + co);
        float x7 = bfld(xlb + (long)s7*HC + co);
        float a0 = redC<C>(lrelu(x0 + xrd) * at);
        float a1 = redC<C>(lrelu(x1 + xrd) * at);
        float a2 = redC<C>(lrelu(x2 + xrd) * at);
        float a3 = redC<C>(lrelu(x3 + xrd) * at);
        float a4 = redC<C>(lrelu(x4 + xrd) * at);
        float a5 = redC<C>(lrelu(x5 + xrd) * at);
        float a6 = redC<C>(lrelu(x6 + xrd) * at);
        float a7 = redC<C>(lrelu(x7 + xrd) * at);
        float p0 = __expf(a0 - m0), p1 = __expf(a1 - m0);
        float p2 = __expf(a2 - m0), p3 = __expf(a3 - m0);
        float p4 = __expf(a4 - m0), p5 = __expf(a5 - m0);
        float p6 = __expf(a6 - m0), p7 = __expf(a7 - m0);
        l += ((p0+p1)+(p2+p3)) + ((p4+p5)+(p6+p7));
        o = fmaf(p0,x0,o); o = fmaf(p1,x1,o); o = fmaf(p2,x2,o); o = fmaf(p3,x3,o);
        o = fmaf(p4,x4,o); o = fmaf(p5,x5,o); o = fmaf(p6,x6,o); o = fmaf(p7,x7,o);
    }
    for (; j < end; j += 4){
        int m = end - j;
        int s0 = srclist[j];
        int s1 = (m > 1) ? srclist[j+1] : s0;
        int s2 = (m > 2) ? srclist[j+2] : s0;
        int s3 = (m > 3) ? srclist[j+3] : s0;
        float x0 = bfld(xlb + (long)s0*HC + co);
        float x1 = bfld(xlb + (long)s1*HC + co);
        float x2 = bfld(xlb + (long)s2*HC + co);
        float x3 = bfld(xlb + (long)s3*HC + co);
        float a0 = redC<C>(lrelu(x0 + xrd) * at);
        float a1 = redC<C>(lrelu(x1 + xrd) * at);
        float a2 = redC<C>(lrelu(x2 + xrd) * at);
        float a3 = redC<C>(lrelu(x3 + xrd) * at);
        float p0 = __expf(a0 - m0);
        float p1 = __expf(a1 - m0);
        float p2 = __expf(a2 - m0);
        float p3 = __expf(a3 - m0);
        l += p0; o = fmaf(p0,x0,o);
        if (m > 1){ l += p1; o = fmaf(p1,x1,o); }
        if (m > 2){ l += p2; o = fmaf(p2,x2,o); }
        if (m > 3){ l += p3; o = fmaf(p3,x3,o); }
    }
    val[rowd] = o * (1.0f/l) + bias[co];
}

// ---------------- layer-3 gat (head-mean, single pass, wave per node) ----------------
__global__ __launch_bounds__(256)
void k_gat3(const int* __restrict__ indptr, const int* __restrict__ srclist,
            const ushort_t* __restrict__ xlb, const float* __restrict__ xr,
            const float* __restrict__ att, const float* __restrict__ bias,
            float* __restrict__ val){
    const int HC = 64;
    const int lane = threadIdx.x & 63;
    const int d = blockIdx.x*4 + (threadIdx.x >> 6);
    const long rowd = (long)d*HC + lane;

    const float xrd = xr[rowd];
    const float at  = att[lane];
    float xls = bfld(xlb + rowd);
    float m0 = redC<8>(lrelu(xls + xrd) * at);
    float l = 1.f, o = xls;

    int j = indptr[d], end = indptr[d+1];
    for (; j + 8 <= end; j += 8){
        int s0 = srclist[j+0], s1 = srclist[j+1], s2 = srclist[j+2], s3 = srclist[j+3];
        int s4 = srclist[j+4], s5 = srclist[j+5], s6 = srclist[j+6], s7 = srclist[j+7];
        float x0 = bfld(xlb + (long)s0*HC + lane);
        float x1 = bfld(xlb + (long)s1*HC + lane);
        float x2 = bfld(xlb + (long)s2*HC + lane);
        float x3 = bfld(xlb + (long)s3*HC + lane);
        float x4 = bfld(xlb + (long)s4*HC + lane);
        float x5 = bfld(xlb + (long)s5*HC + lane);
        float x6 = bfld(xlb + (long)s6*HC + lane);
        float x7 = bfld(xlb + (long)s7*HC + lane);
        float a0 = redC<8>(lrelu(x0 + xrd) * at);
        float a1 = redC<8>(lrelu(x1 + xrd) * at);
        float a2 = redC<8>(lrelu(x2 + xrd) * at);
        float a3 = redC<8>(lrelu(x3 + xrd) * at);
        float a4 = redC<8>(lrelu(x4 + xrd) * at);
        float a5 = redC<8>(lrelu(x5 + xrd) * at);
        float a6 = redC<8>(lrelu(x6 + xrd) * at);
        float a7 = redC<8>(lrelu(x7 + xrd) * at);
        float p0 = __expf(a0 - m0), p1 = __expf(a1 - m0);
        float p2 = __expf(a2 - m0), p3 = __expf(a3 - m0);
        float p4 = __expf(a4 - m0), p5 = __expf(a5 - m0);
        float p6 = __expf(a6 - m0), p7 = __expf(a7 - m0);
        l += ((p0+p1)+(p2+p3)) + ((p4+p5)+(p6+p7));
        o = fmaf(p0,x0,o); o = fmaf(p1,x1,o); o = fmaf(p2,x2,o); o = fmaf(p3,x3,o);
        o = fmaf(p4,x4,o); o = fmaf(p5,x5,o); o = fmaf(p6,x6,o); o = fmaf(p7,x7,o);
    }
    for (; j < end; j += 4){
        int m = end - j;
        int s0 = srclist[j];
        int s1 = (m > 1) ? srclist[j+1] : s0;
        int s2 = (m > 2) ? srclist[j+2] : s0;
        int s3 = (m > 3) ? srclist[j+3] : s0;
        float x0 = bfld(xlb + (long)s0*HC + lane);
        float x1 = bfld(xlb + (long)s1*HC + lane);
        float x2 = bfld(xlb + (long)s2*HC + lane);
        float x3 = bfld(xlb + (long)s3*HC + lane);
        float a0 = redC<8>(lrelu(x0 + xrd) * at);
        float a1 = redC<8>(lrelu(x1 + xrd) * at);
        float a2 = redC<8>(lrelu(x2 + xrd) * at);
        float a3 = redC<8>(lrelu(x3 + xrd) * at);
        float p0 = __expf(a0 - m0);
        float p1 = __expf(a1 - m0);
        float p2 = __expf(a2 - m0);
        float p3 = __expf(a3 - m0);
        l += p0; o = fmaf(p0,x0,o);
        if (m > 1){ l += p1; o = fmaf(p1,x1,o); }
        if (m > 2){ l += p2; o = fmaf(p2,x2,o); }
        if (m > 3){ l += p3; o = fmaf(p3,x3,o); }
    }
    float r = o * (1.0f/l);
    r += __shfl_xor(r, 8);
    r += __shfl_xor(r, 16);
    r += __shfl_xor(r, 32);
    if (lane < 8) val[(long)d*8 + lane] = r*0.125f + bias[lane];
}

// ---------------- GraphNorm stats: chunked partials + finalize (self-zeroing) ----------------
template<int F>
__global__ void k_gn_partial(const float* __restrict__ val,
                             const int* __restrict__ gstart, const int* __restrict__ gend,
                             float* __restrict__ gsum, float* __restrict__ gsq){
    int g = blockIdx.x, ch = blockIdx.y, nch = gridDim.y;
    int c = threadIdx.x;
    int s = gstart[g], e = gend[g];
    float sum = 0.f, sq = 0.f;
    for (int i = s + ch; i < e; i += nch){
        float v = val[(long)i*F + c];
        sum += v; sq += v*v;
    }
    if (sum != 0.f || sq != 0.f){
        atomicAdd(&gsum[g*F + c], sum);
        atomicAdd(&gsq[g*F + c], sq);
    }
}

__global__ void k_gn_finalize(float* __restrict__ gsum, float* __restrict__ gsq,
                              const int* __restrict__ gstart, const int* __restrict__ gend,
                              const float* __restrict__ ms,
                              float* __restrict__ gmu, float* __restrict__ ginv, int F){
    int idx = blockIdx.x*blockDim.x + threadIdx.x;
    if (idx >= GG*F) return;
    int g = idx / F, c = idx - g*F;
    int cnti = gend[g] - gstart[g];
    float cn = cnti > 0 ? (float)cnti : 1.f;
    float mean = gsum[idx] / cn;
    float mu = mean * ms[c];
    float var = gsq[idx]/cn - 2.f*mu*mean + mu*mu;
    gmu[idx]  = mu;
    ginv[idx] = rsqrtf(var + EPSV);
    gsum[idx] = 0.f;
    gsq[idx]  = 0.f;
}

// ---------------- fused tail: layer-3 GraphNorm stats + norm+relu pool + logits ----------------
__global__ void k_tail(const float* __restrict__ D,
                       const int* __restrict__ gstart, const int* __restrict__ gend,
                       const float* __restrict__ ms, const float* __restrict__ w,
                       const float* __restrict__ b,
                       const float* __restrict__ lw, const float* __restrict__ lb,
                       float* __restrict__ outLog, float* __restrict__ outFeat){
    int g = blockIdx.x;
    int t = threadIdx.x;
    int c = t & 7, r = t >> 3;
    int s = gstart[g], e = gend[g];
    int cnti = e - s;
    float cn = cnti > 0 ? (float)cnti : 1.f;

    float sum = 0.f, sq = 0.f;
    for (int i = s + r; i < e; i += 8){
        float v = D[(long)i*8 + c];
        sum += v; sq += v*v;
    }
    #pragma unroll
    for (int mask = 8; mask < 64; mask <<= 1){
        sum += __shfl_xor(sum, mask, 64);
        sq  += __shfl_xor(sq,  mask, 64);
    }
    float mean = sum / cn;
    float mu = mean * ms[c];
    float var = sq/cn - 2.f*mu*mean + mu*mu;
    float iv = rsqrtf(var + EPSV);
    float wc = w[c], bc = b[c];

    float psum = 0.f;
    for (int i = s + r; i < e; i += 8){
        float v = (D[(long)i*8 + c] - mu) * iv * wc + bc;
        psum += fmaxf(v, 0.f);
    }
    #pragma unroll
    for (int mask = 8; mask < 64; mask <<= 1)
        psum += __shfl_xor(psum, mask, 64);
    float feat = psum / cn;

    if (t < 8) outFeat[g*8 + t] = feat;

    float a = 0.f;
    int jj = t;
    if (t < 4) a = lb[jj];
    #pragma unroll
    for (int cc = 0; cc < 8; ++cc){
        float fc = __shfl(feat, cc, 64);
        if (t < 4) a += fc * lw[cc*4 + jj];
    }
    if (t < 4) outLog[g*4 + jj] = a;
}

extern "C" void kernel_launch(void* const* d_in, const int* in_sizes, int n_in,
                              void* d_out, int out_size, void* d_ws, size_t ws_size,
                              hipStream_t stream) {
    const float* x     = (const float*)d_in[0];
    const int*   ei    = (const int*)  d_in[1];
    const int*   batch = (const int*)  d_in[2];
    const float* W1l = (const float*)d_in[3];  const float* b1l = (const float*)d_in[4];
    const float* W1r = (const float*)d_in[5];  const float* b1r = (const float*)d_in[6];
    const float* att1= (const float*)d_in[7];  const float* bias1=(const float*)d_in[8];
    const float* g1w = (const float*)d_in[9];  const float* g1b = (const float*)d_in[10];
    const float* g1m = (const float*)d_in[11];
    const float* W2l = (const float*)d_in[12]; const float* b2l = (const float*)d_in[13];
    const float* W2r = (const float*)d_in[14]; const float* b2r = (const float*)d_in[15];
    const float* att2= (const float*)d_in[16]; const float* bias2=(const float*)d_in[17];
    const float* g2w = (const float*)d_in[18]; const float* g2b = (const float*)d_in[19];
    const float* g2m = (const float*)d_in[20];
    const float* W3l = (const float*)d_in[21]; const float* b3l = (const float*)d_in[22];
    const float* W3r = (const float*)d_in[23]; const float* b3r = (const float*)d_in[24];
    const float* att3= (const float*)d_in[25]; const float* bias3=(const float*)d_in[26];
    const float* g3w = (const float*)d_in[27]; const float* g3b = (const float*)d_in[28];
    const float* g3m = (const float*)d_in[29];
    const float* lin_w=(const float*)d_in[30]; const float* lin_b=(const float*)d_in[31];

    const int* esrc = ei;
    const int* edst = ei + EE;

    // ---- workspace arena (units of 4B) ----
    float* ws = (float*)d_ws;
    int*   cursor  = (int*)(ws + 0);         // 20480
    int*   indptr  = (int*)(ws + 20480);     // 20480
    int*   srclist = (int*)(ws + 40960);     // 320512
    int*   gstart  = (int*)(ws + 361472);    // 512
    int*   gend    = (int*)(ws + 361984);    // 512
    float* gmu     = ws + 362496;            // 16384
    float* ginv    = ws + 378880;            // 16384
    float* gsumP   = ws + 395264;            // 16384
    float* gsqP    = ws + 411648;            // 16384
    ushort_t* W1hi = (ushort_t*)(ws + 428032);
    ushort_t* W1lo = (ushort_t*)(ws + 436224);
    ushort_t* W2hi = (ushort_t*)(ws + 444416);
    ushort_t* W2lo = (ushort_t*)(ws + 477184);
    ushort_t* W3hi = (ushort_t*)(ws + 509952);
    ushort_t* W3lo = (ushort_t*)(ws + 518144);
    ushort_t* Bb = (ushort_t*)(ws + 526336);    // xl bf16
    float* Cb = ws + 3086336;                   // xr fp32
    float* D  = ws + 8206336;                   // pre-norm GAT out

    const int TB = 256;
    const int MBm = (NN + 63)/64;    // 313
    const int NCH = 32;

    // 1: weight prep + cursor zeroing
    k_wprep_all<<<gridFor(NN, TB), TB, 0, stream>>>(W1l, W1r, W2l, W2r, W3l, W3r,
        W1hi, W1lo, W2hi, W2lo, W3hi, W3lo, cursor);
    // 2: degree count + graph bounds + gn-partial zero
    k_degbounds<<<gridFor(EE, TB), TB, 0, stream>>>(edst, cursor, batch, gstart, gend, gsumP);
    // 3: scan (int4-vectorized; re-zeroes cursor)
    k_scan<<<1, 1024, 0, stream>>>(cursor, indptr);
    // 4: gemm1 + scatter fused (independent work, one dispatch)
    {
        int nGemm = MBm*4;
        int nScat = gridFor(EE, TB);
        k_gemm1_scatter<<<nGemm + nScat, 256, 0, stream>>>(x, W1hi, W1lo, b1l, b1r,
            Bb, Cb, esrc, edst, indptr, cursor, srclist, nGemm, MBm);
    }

    // ---- layer 1 rest ----
    k_gat_s<32><<<dim3(NN/4, 4), 256, 0, stream>>>(indptr, srclist, Bb, Cb, att1, bias1, D, 256);
    k_gn_partial<256><<<dim3(GG, NCH), 256, 0, stream>>>(D, gstart, gend, gsumP, gsqP);
    k_gn_finalize<<<gridFor(GG*256, TB), TB, 0, stream>>>(gsumP, gsqP, gstart, gend, g1m, gmu, ginv, 256);

    // ---- layer 2 ----
    k_gemm_mfma<true><<<dim3(MBm, 2), 256, 0, stream>>>(D, W2hi, W2lo, b2l, b2r,
        gmu, ginv, g1w, g1b, batch, Bb, Cb, 256, 256, 128);
    k_gat_s<16><<<dim3(NN/4, 2), 256, 0, stream>>>(indptr, srclist, Bb, Cb, att2, bias2, D, 128);
    k_gn_partial<128><<<dim3(GG, NCH), 128, 0, stream>>>(D, gstart, gend, gsumP, gsqP);
    k_gn_finalize<<<gridFor(GG*128, TB), TB, 0, stream>>>(gsumP, gsqP, gstart, gend, g2m, gmu, ginv, 128);

    // ---- layer 3 ----
    k_gemm_mfma<true><<<dim3(MBm, 1), 256, 0, stream>>>(D, W3hi, W3lo, b3l, b3r,
        gmu, ginv, g2w, g2b, batch, Bb, Cb, 128, 128, 64);
    k_gat3<<<NN/4, 256, 0, stream>>>(indptr, srclist, Bb, Cb, att3, bias3, D);

    // ---- fused tail ----
    float* outLog  = (float*)d_out;
    float* outFeat = outLog + GG*4;
    k_tail<<<GG, 64, 0, stream>>>(D, gstart, gend, g3m, g3w, g3b, lin_w, lin_b, outLog, outFeat);
}

// Round 13
// 324.332 us; speedup vs baseline: 1.1839x; 1.1839x over previous
//
#include <hip/hip_runtime.h>
#include <math.h>

#define NN 20000
#define EE 320000
#define GG 64
#define HH 8
#define EPSV 1e-5f

static inline unsigned int gridFor(long n, int b){ return (unsigned int)((n + b - 1)/b); }

typedef __attribute__((ext_vector_type(8))) short short8;
typedef __attribute__((ext_vector_type(4))) float f32x4;
typedef unsigned short ushort_t;

// ---------------- bf16 helpers ----------------
__device__ __forceinline__ float asf(unsigned int u){
    union{unsigned int i; float f;} c; c.i = u; return c.f;
}
__device__ __forceinline__ ushort_t f2bf(float x){   // RNE
    unsigned u = __float_as_uint(x);
    unsigned r = u + 0x7FFFu + ((u >> 16) & 1u);
    return (ushort_t)(r >> 16);
}
__device__ __forceinline__ void split_bf16(float x, short& hi, short& lo){
    unsigned u = __float_as_uint(x);
    unsigned r = u + 0x7FFFu + ((u >> 16) & 1u);
    hi = (short)(r >> 16);
    float hf = asf(((unsigned)(unsigned short)hi) << 16);
    float res = x - hf;
    unsigned u2 = __float_as_uint(res);
    unsigned r2 = u2 + 0x7FFFu + ((u2 >> 16) & 1u);
    lo = (short)(r2 >> 16);
}

// ---------------- weight prep (all 3 layers) + cursor zeroing ----------------
__device__ __forceinline__ void wprep_one(const float* Wl, const float* Wr,
                                          ushort_t* Whi, ushort_t* Wlo,
                                          int K, int Kp, int HC, int t){
    int octs = Kp >> 3;
    int n = t / octs, ko = t - n*octs;
    int kb = ko*8;
    const float* W = (n < HC) ? (Wl + n) : (Wr + (n - HC));
    short hi[8], lo[8];
    #pragma unroll
    for (int j = 0; j < 8; ++j){
        int k = kb + j;
        float v = (k < K) ? W[(long)k*HC] : 0.f;
        split_bf16(v, hi[j], lo[j]);
    }
    long base = (((long)(n>>4)*(Kp>>5) + (kb>>5))*64 + (n&15) + 16*((kb>>3)&3))*8;
    *(short8*)&Whi[base] = *(short8*)hi;
    *(short8*)&Wlo[base] = *(short8*)lo;
}

#define WP1 2048
#define WP2 8192
#define WP3 2048

__global__ void k_wprep_all(const float* __restrict__ W1l, const float* __restrict__ W1r,
                            const float* __restrict__ W2l, const float* __restrict__ W2r,
                            const float* __restrict__ W3l, const float* __restrict__ W3r,
                            ushort_t* __restrict__ W1hi, ushort_t* __restrict__ W1lo,
                            ushort_t* __restrict__ W2hi, ushort_t* __restrict__ W2lo,
                            ushort_t* __restrict__ W3hi, ushort_t* __restrict__ W3lo,
                            int* __restrict__ cursor){
    int t = blockIdx.x*blockDim.x + threadIdx.x;
    if (t < NN) cursor[t] = 0;
    if (t < WP1) wprep_one(W1l, W1r, W1hi, W1lo, 19, 32, 256, t);
    else if (t < WP1+WP2) wprep_one(W2l, W2r, W2hi, W2lo, 256, 256, 128, t-WP1);
    else if (t < WP1+WP2+WP3) wprep_one(W3l, W3r, W3hi, W3lo, 128, 128, 64, t-WP1-WP2);
}

// ---------------- degree count + graph bounds + gn-partial zeroing ----------------
__global__ void k_degbounds(const int* __restrict__ edst, int* __restrict__ deg,
                            const int* __restrict__ batch,
                            int* __restrict__ gstart, int* __restrict__ gend,
                            float* __restrict__ gz){
    int e = blockIdx.x*blockDim.x + threadIdx.x;
    if (e < EE) atomicAdd(&deg[edst[e]], 1);
    if (e < NN){
        int b = batch[e];
        if (e == 0 || batch[e-1] != b) gstart[b] = e;
        if (e == NN-1 || batch[e+1] != b) gend[b] = e+1;
    }
    if (e < 2*GG*256) gz[e] = 0.f;
}

// ---------------- exclusive scan, int4-vectorized (NN = 1000*20 exactly) ----------------
__global__ void k_scan(int* __restrict__ deg, int* __restrict__ indptr){
    __shared__ int partial[1024];
    int t = threadIdx.x;
    int vals[20];
    int sum = 0;
    if (t < 1000){
        int4 buf[5];
        const int4* p = (const int4*)(deg + t*20);
        #pragma unroll
        for (int i = 0; i < 5; ++i) buf[i] = p[i];
        const int* bv = (const int*)buf;
        #pragma unroll
        for (int i = 0; i < 20; ++i){ vals[i] = sum; sum += bv[i]; }
        int4 z = make_int4(0,0,0,0);
        int4* pz = (int4*)(deg + t*20);
        #pragma unroll
        for (int i = 0; i < 5; ++i) pz[i] = z;
    }
    partial[t] = sum;
    __syncthreads();
    for (int off = 1; off < 1024; off <<= 1){
        int v = (t >= off) ? partial[t-off] : 0;
        __syncthreads();
        partial[t] += v;
        __syncthreads();
    }
    int prefix = (t > 0) ? partial[t-1] : 0;
    if (t < 1000){
        int out[20];
        #pragma unroll
        for (int i = 0; i < 20; ++i) out[i] = prefix + vals[i];
        int4* q = (int4*)(indptr + t*20);
        #pragma unroll
        for (int i = 0; i < 5; ++i) q[i] = ((const int4*)out)[i];
    }
    if (t == 1023) indptr[NN] = prefix;
}

// ---------------- bf16-split MFMA dual linear body ----------------
template<bool NORM>
__device__ __forceinline__ void gemm_body(
    const float* __restrict__ h,
    const ushort_t* __restrict__ Whi, const ushort_t* __restrict__ Wlo,
    const float* __restrict__ bl, const float* __restrict__ br,
    const float* __restrict__ gmu, const float* __restrict__ ginv,
    const float* __restrict__ nw, const float* __restrict__ nb,
    const int* __restrict__ batch,
    ushort_t* __restrict__ xlb, float* __restrict__ xr,
    int K, int Kp, int HC, int bm, int bn){
    __shared__ short Ahi[2][64*32], Alo[2][64*32];
    const int tid  = threadIdx.x;
    const int lane = tid & 63;
    const int wave = tid >> 6;
    const int m0   = bm * 64;
    const int n0   = bn * 128;
    const int wr   = (wave & 1) * 32;
    const int wcg  = (wave >> 1) * 64;
    const int kblocks = Kp >> 5;

    const int srow = tid >> 2;
    const int soct = tid & 3;

    f32x4 acc[2][4] = {};

    for (int kb = 0; kb < kblocks; ++kb){
        int p = kb & 1;
        int k0 = kb*32;
        {
            int gm = m0 + srow;
            int kbase = k0 + soct*8;
            float v[8];
            const float* src = h + (long)gm*K + kbase;
            if (gm < NN && kbase + 8 <= K){
                float4 t0 = *(const float4*)src;
                float4 t1 = *(const float4*)(src+4);
                v[0]=t0.x; v[1]=t0.y; v[2]=t0.z; v[3]=t0.w;
                v[4]=t1.x; v[5]=t1.y; v[6]=t1.z; v[7]=t1.w;
            } else {
                #pragma unroll
                for (int j = 0; j < 8; ++j)
                    v[j] = (gm < NN && kbase + j < K) ? src[j] : 0.f;
            }
            if (NORM && gm < NN){
                int g = batch[gm];
                const float* mu = gmu + (long)g*K;
                const float* iv = ginv + (long)g*K;
                #pragma unroll
                for (int j = 0; j < 8; ++j){
                    int c = kbase + j;
                    float t = (v[j] - mu[c]) * iv[c] * nw[c] + nb[c];
                    v[j] = fmaxf(t, 0.f);
                }
            }
            short hi[8], lo[8];
            #pragma unroll
            for (int j = 0; j < 8; ++j) split_bf16(v[j], hi[j], lo[j]);
            long off = ((long)(srow>>4)*64 + (srow&15) + 16*soct)*8;
            *(short8*)&Ahi[p][off] = *(short8*)hi;
            *(short8*)&Alo[p][off] = *(short8*)lo;
        }
        __syncthreads();

        int rb0 = wr >> 4;
        short8 ah0 = *(short8*)&Ahi[p][((rb0  )*64 + lane)*8];
        short8 ah1 = *(short8*)&Ahi[p][((rb0+1)*64 + lane)*8];
        short8 al0 = *(short8*)&Alo[p][((rb0  )*64 + lane)*8];
        short8 al1 = *(short8*)&Alo[p][((rb0+1)*64 + lane)*8];

        short8 bh[4], bl_[4];
        #pragma unroll
        for (int j = 0; j < 4; ++j){
            int n = n0 + wcg + j*16;
            long bbase = (((long)(n>>4)*kblocks + kb)*64 + lane)*8;
            bh[j]  = *(const short8*)&Whi[bbase];
            bl_[j] = *(const short8*)&Wlo[bbase];
        }

        #pragma unroll
        for (int j = 0; j < 4; ++j){
            acc[0][j] = __builtin_amdgcn_mfma_f32_16x16x32_bf16(al0, bh[j],  acc[0][j], 0,0,0);
            acc[0][j] = __builtin_amdgcn_mfma_f32_16x16x32_bf16(ah0, bl_[j], acc[0][j], 0,0,0);
            acc[0][j] = __builtin_amdgcn_mfma_f32_16x16x32_bf16(ah0, bh[j],  acc[0][j], 0,0,0);
            acc[1][j] = __builtin_amdgcn_mfma_f32_16x16x32_bf16(al1, bh[j],  acc[1][j], 0,0,0);
            acc[1][j] = __builtin_amdgcn_mfma_f32_16x16x32_bf16(ah1, bl_[j], acc[1][j], 0,0,0);
            acc[1][j] = __builtin_amdgcn_mfma_f32_16x16x32_bf16(ah1, bh[j],  acc[1][j], 0,0,0);
        }
    }

    #pragma unroll
    for (int i = 0; i < 2; ++i){
        int row0 = m0 + wr + i*16 + (lane >> 4)*4;
        #pragma unroll
        for (int j = 0; j < 4; ++j){
            int n = n0 + wcg + j*16 + (lane & 15);
            float bb = (n < HC) ? bl[n] : br[n - HC];
            #pragma unroll
            for (int r = 0; r < 4; ++r){
                int gm = row0 + r;
                if (gm >= NN) continue;
                float v = acc[i][j][r] + bb;
                if (n < HC) xlb[(long)gm*HC + n] = f2bf(v);
                else        xr[(long)gm*HC + (n - HC)] = v;
            }
        }
    }
}

template<bool NORM>
__global__ __launch_bounds__(256)
void k_gemm_mfma(const float* __restrict__ h,
                 const ushort_t* __restrict__ Whi, const ushort_t* __restrict__ Wlo,
                 const float* __restrict__ bl, const float* __restrict__ br,
                 const float* __restrict__ gmu, const float* __restrict__ ginv,
                 const float* __restrict__ nw, const float* __restrict__ nb,
                 const int* __restrict__ batch,
                 ushort_t* __restrict__ xlb, float* __restrict__ xr,
                 int K, int Kp, int HC){
    gemm_body<NORM>(h, Whi, Wlo, bl, br, gmu, ginv, nw, nb, batch, xlb, xr,
                    K, Kp, HC, blockIdx.x, blockIdx.y);
}

// gemm1 + scatter in one dispatch (independent work, concurrent pipes)
__global__ __launch_bounds__(256)
void k_gemm1_scatter(const float* __restrict__ x,
                     const ushort_t* __restrict__ Whi, const ushort_t* __restrict__ Wlo,
                     const float* __restrict__ bl, const float* __restrict__ br,
                     ushort_t* __restrict__ xlb, float* __restrict__ xr,
                     const int* __restrict__ esrc, const int* __restrict__ edst,
                     const int* __restrict__ indptr, int* __restrict__ cursor,
                     int* __restrict__ srclist, int nGemm, int mb){
    if ((int)blockIdx.x < nGemm){
        gemm_body<false>(x, Whi, Wlo, bl, br, nullptr, nullptr, nullptr, nullptr,
                         nullptr, xlb, xr, 19, 32, 256, blockIdx.x % mb, blockIdx.x / mb);
    } else {
        int e = (blockIdx.x - nGemm)*256 + threadIdx.x;
        if (e < EE){
            int d = edst[e];
            int pos = atomicAdd(&cursor[d], 1);
            srclist[indptr[d] + pos] = esrc[e];
        }
    }
}

// ---------------- fused GATv2, wave-per-node, VEC channels/lane, bf16 gather ----------------
template<int VEC> struct VT;
template<> struct VT<1>{ using T = float;  };
template<> struct VT<2>{ using T = float2; };
template<> struct VT<4>{ using T = float4; };

template<int VEC> struct BF;
template<> struct BF<1>{
    static __device__ __forceinline__ float load(const ushort_t* p){
        return asf(((unsigned)*p) << 16);
    }
};
template<> struct BF<2>{
    static __device__ __forceinline__ float2 load(const ushort_t* p){
        unsigned u = *(const unsigned*)p;
        return make_float2(asf(u << 16), asf(u & 0xFFFF0000u));
    }
};
template<> struct BF<4>{
    static __device__ __forceinline__ float4 load(const ushort_t* p){
        uint2 u = *(const uint2*)p;
        return make_float4(asf(u.x << 16), asf(u.x & 0xFFFF0000u),
                           asf(u.y << 16), asf(u.y & 0xFFFF0000u));
    }
};

__device__ __forceinline__ float lrelu(float z){ return z > 0.f ? z : 0.2f*z; }

__device__ __forceinline__ float edot(float xv, float xr, float at){
    return lrelu(xv + xr) * at;
}
__device__ __forceinline__ float edot(float2 xv, float2 xr, float2 at){
    return lrelu(xv.x+xr.x)*at.x + lrelu(xv.y+xr.y)*at.y;
}
__device__ __forceinline__ float edot(float4 xv, float4 xr, float4 at){
    return lrelu(xv.x+xr.x)*at.x + lrelu(xv.y+xr.y)*at.y
         + lrelu(xv.z+xr.z)*at.z + lrelu(xv.w+xr.w)*at.w;
}
__device__ __forceinline__ void efma(float& o, float p, float xv){ o = fmaf(p,xv,o); }
__device__ __forceinline__ void efma(float2& o, float p, float2 xv){
    o.x = fmaf(p,xv.x,o.x); o.y = fmaf(p,xv.y,o.y);
}
__device__ __forceinline__ void efma(float4& o, float p, float4 xv){
    o.x = fmaf(p,xv.x,o.x); o.y = fmaf(p,xv.y,o.y);
    o.z = fmaf(p,xv.z,o.z); o.w = fmaf(p,xv.w,o.w);
}
__device__ __forceinline__ float escale(float o, float s, float b){ return fmaf(o,s,b); }
__device__ __forceinline__ float2 escale(float2 o, float s, float2 b){
    return make_float2(fmaf(o.x,s,b.x), fmaf(o.y,s,b.y));
}
__device__ __forceinline__ float4 escale(float4 o, float s, float4 b){
    return make_float4(fmaf(o.x,s,b.x), fmaf(o.y,s,b.y), fmaf(o.z,s,b.z), fmaf(o.w,s,b.w));
}

__device__ __forceinline__ float red8(float v){
    v += __shfl_xor(v, 1);
    v += __shfl_xor(v, 2);
    v += __shfl_xor(v, 4);
    return v;
}

template<int VEC, bool MEAN>
__global__ __launch_bounds__(256)
void k_gat_w(const int* __restrict__ indptr, const int* __restrict__ srclist,
             const ushort_t* __restrict__ xlb, const float* __restrict__ xr,
             const float* __restrict__ att, const float* __restrict__ bias,
             float* __restrict__ val){
    using V = typename VT<VEC>::T;
    constexpr int HC = 64*VEC;
    const int lane = threadIdx.x & 63;
    const int d = blockIdx.x*4 + (threadIdx.x >> 6);
    const int co = lane*VEC;

    V xrd = *(const V*)&xr[(long)d*HC + co];
    V at  = *(const V*)&att[co];
    V xls = BF<VEC>::load(xlb + (long)d*HC + co);

    float m0 = red8(edot(xls, xrd, at));
    float l = 1.0f;
    V o = xls;

    int j = indptr[d], end = indptr[d+1];   // wave-uniform
    for (; j + 8 <= end; j += 8){
        int s0 = srclist[j+0], s1 = srclist[j+1], s2 = srclist[j+2], s3 = srclist[j+3];
        int s4 = srclist[j+4], s5 = srclist[j+5], s6 = srclist[j+6], s7 = srclist[j+7];
        V x0 = BF<VEC>::load(xlb + (long)s0*HC + co);
        V x1 = BF<VEC>::load(xlb + (long)s1*HC + co);
        V x2 = BF<VEC>::load(xlb + (long)s2*HC + co);
        V x3 = BF<VEC>::load(xlb + (long)s3*HC + co);
        V x4 = BF<VEC>::load(xlb + (long)s4*HC + co);
        V x5 = BF<VEC>::load(xlb + (long)s5*HC + co);
        V x6 = BF<VEC>::load(xlb + (long)s6*HC + co);
        V x7 = BF<VEC>::load(xlb + (long)s7*HC + co);
        float a0 = red8(edot(x0, xrd, at));
        float a1 = red8(edot(x1, xrd, at));
        float a2 = red8(edot(x2, xrd, at));
        float a3 = red8(edot(x3, xrd, at));
        float a4 = red8(edot(x4, xrd, at));
        float a5 = red8(edot(x5, xrd, at));
        float a6 = red8(edot(x6, xrd, at));
        float a7 = red8(edot(x7, xrd, at));
        float p0 = __expf(a0 - m0), p1 = __expf(a1 - m0);
        float p2 = __expf(a2 - m0), p3 = __expf(a3 - m0);
        float p4 = __expf(a4 - m0), p5 = __expf(a5 - m0);
        float p6 = __expf(a6 - m0), p7 = __expf(a7 - m0);
        l += ((p0+p1)+(p2+p3)) + ((p4+p5)+(p6+p7));
        efma(o, p0, x0); efma(o, p1, x1); efma(o, p2, x2); efma(o, p3, x3);
        efma(o, p4, x4); efma(o, p5, x5); efma(o, p6, x6); efma(o, p7, x7);
    }
    for (; j < end; j += 4){
        int m = end - j;
        int s0 = srclist[j];
        int s1 = (m > 1) ? srclist[j+1] : s0;
        int s2 = (m > 2) ? srclist[j+2] : s0;
        int s3 = (m > 3) ? srclist[j+3] : s0;
        V x0 = BF<VEC>::load(xlb + (long)s0*HC + co);
        V x1 = BF<VEC>::load(xlb + (long)s1*HC + co);
        V x2 = BF<VEC>::load(xlb + (long)s2*HC + co);
        V x3 = BF<VEC>::load(xlb + (long)s3*HC + co);
        float a0 = red8(edot(x0, xrd, at));
        float a1 = red8(edot(x1, xrd, at));
        float a2 = red8(edot(x2, xrd, at));
        float a3 = red8(edot(x3, xrd, at));
        float p0 = __expf(a0 - m0);
        float p1 = __expf(a1 - m0);
        float p2 = __expf(a2 - m0);
        float p3 = __expf(a3 - m0);
        l += p0; efma(o, p0, x0);
        if (m > 1){ l += p1; efma(o, p1, x1); }
        if (m > 2){ l += p2; efma(o, p2, x2); }
        if (m > 3){ l += p3; efma(o, p3, x3); }
    }
    float invl = 1.0f / l;
    if (!MEAN){
        V bv = *(const V*)&bias[co];
        *(V*)&val[(long)d*HC + co] = escale(o, invl, bv);
    } else {
        float r = ((float&)o) * invl;
        r += __shfl_xor(r, 8);
        r += __shfl_xor(r, 16);
        r += __shfl_xor(r, 32);
        if (lane < 8) val[(long)d*8 + lane] = r*0.125f + bias[lane];
    }
}

// ---------------- GraphNorm stats: chunked partials + finalize (self-zeroing) ----------------
template<int F>
__global__ void k_gn_partial(const float* __restrict__ val,
                             const int* __restrict__ gstart, const int* __restrict__ gend,
                             float* __restrict__ gsum, float* __restrict__ gsq){
    int g = blockIdx.x, ch = blockIdx.y, nch = gridDim.y;
    int c = threadIdx.x;
    int s = gstart[g], e = gend[g];
    float sum = 0.f, sq = 0.f;
    for (int i = s + ch; i < e; i += nch){
        float v = val[(long)i*F + c];
        sum += v; sq += v*v;
    }
    if (sum != 0.f || sq != 0.f){
        atomicAdd(&gsum[g*F + c], sum);
        atomicAdd(&gsq[g*F + c], sq);
    }
}

__global__ void k_gn_finalize(float* __restrict__ gsum, float* __restrict__ gsq,
                              const int* __restrict__ gstart, const int* __restrict__ gend,
                              const float* __restrict__ ms,
                              float* __restrict__ gmu, float* __restrict__ ginv, int F){
    int idx = blockIdx.x*blockDim.x + threadIdx.x;
    if (idx >= GG*F) return;
    int g = idx / F, c = idx - g*F;
    int cnti = gend[g] - gstart[g];
    float cn = cnti > 0 ? (float)cnti : 1.f;
    float mean = gsum[idx] / cn;
    float mu = mean * ms[c];
    float var = gsq[idx]/cn - 2.f*mu*mean + mu*mu;
    gmu[idx]  = mu;
    ginv[idx] = rsqrtf(var + EPSV);
    gsum[idx] = 0.f;
    gsq[idx]  = 0.f;
}

// ---------------- fused tail: layer-3 GraphNorm stats + norm+relu pool + logits ----------------
__global__ void k_tail(const float* __restrict__ D,
                       const int* __restrict__ gstart, const int* __restrict__ gend,
                       const float* __restrict__ ms, const float* __restrict__ w,
                       const float* __restrict__ b,
                       const float* __restrict__ lw, const float* __restrict__ lb,
                       float* __restrict__ outLog, float* __restrict__ outFeat){
    int g = blockIdx.x;
    int t = threadIdx.x;
    int c = t & 7, r = t >> 3;
    int s = gstart[g], e = gend[g];
    int cnti = e - s;
    float cn = cnti > 0 ? (float)cnti : 1.f;

    float sum = 0.f, sq = 0.f;
    for (int i = s + r; i < e; i += 8){
        float v = D[(long)i*8 + c];
        sum += v; sq += v*v;
    }
    #pragma unroll
    for (int mask = 8; mask < 64; mask <<= 1){
        sum += __shfl_xor(sum, mask, 64);
        sq  += __shfl_xor(sq,  mask, 64);
    }
    float mean = sum / cn;
    float mu = mean * ms[c];
    float var = sq/cn - 2.f*mu*mean + mu*mu;
    float iv = rsqrtf(var + EPSV);
    float wc = w[c], bc = b[c];

    float psum = 0.f;
    for (int i = s + r; i < e; i += 8){
        float v = (D[(long)i*8 + c] - mu) * iv * wc + bc;
        psum += fmaxf(v, 0.f);
    }
    #pragma unroll
    for (int mask = 8; mask < 64; mask <<= 1)
        psum += __shfl_xor(psum, mask, 64);
    float feat = psum / cn;

    if (t < 8) outFeat[g*8 + t] = feat;

    float a = 0.f;
    int jj = t;
    if (t < 4) a = lb[jj];
    #pragma unroll
    for (int cc = 0; cc < 8; ++cc){
        float fc = __shfl(feat, cc, 64);
        if (t < 4) a += fc * lw[cc*4 + jj];
    }
    if (t < 4) outLog[g*4 + jj] = a;
}

extern "C" void kernel_launch(void* const* d_in, const int* in_sizes, int n_in,
                              void* d_out, int out_size, void* d_ws, size_t ws_size,
                              hipStream_t stream) {
    const float* x     = (const float*)d_in[0];
    const int*   ei    = (const int*)  d_in[1];
    const int*   batch = (const int*)  d_in[2];
    const float* W1l = (const float*)d_in[3];  const float* b1l = (const float*)d_in[4];
    const float* W1r = (const float*)d_in[5];  const float* b1r = (const float*)d_in[6];
    const float* att1= (const float*)d_in[7];  const float* bias1=(const float*)d_in[8];
    const float* g1w = (const float*)d_in[9];  const float* g1b = (const float*)d_in[10];
    const float* g1m = (const float*)d_in[11];
    const float* W2l = (const float*)d_in[12]; const float* b2l = (const float*)d_in[13];
    const float* W2r = (const float*)d_in[14]; const float* b2r = (const float*)d_in[15];
    const float* att2= (const float*)d_in[16]; const float* bias2=(const float*)d_in[17];
    const float* g2w = (const float*)d_in[18]; const float* g2b = (const float*)d_in[19];
    const float* g2m = (const float*)d_in[20];
    const float* W3l = (const float*)d_in[21]; const float* b3l = (const float*)d_in[22];
    const float* W3r = (const float*)d_in[23]; const float* b3r = (const float*)d_in[24];
    const float* att3= (const float*)d_in[25]; const float* bias3=(const float*)d_in[26];
    const float* g3w = (const float*)d_in[27]; const float* g3b = (const float*)d_in[28];
    const float* g3m = (const float*)d_in[29];
    const float* lin_w=(const float*)d_in[30]; const float* lin_b=(const float*)d_in[31];

    const int* esrc = ei;
    const int* edst = ei + EE;

    // ---- workspace arena (units of 4B) ----
    float* ws = (float*)d_ws;
    int*   cursor  = (int*)(ws + 0);
    int*   indptr  = (int*)(ws + 20480);
    int*   srclist = (int*)(ws + 40960);
    int*   gstart  = (int*)(ws + 361472);
    int*   gend    = (int*)(ws + 361984);
    float* gmu     = ws + 362496;
    float* ginv    = ws + 378880;
    float* gsumP   = ws + 395264;
    float* gsqP    = ws + 411648;
    ushort_t* W1hi = (ushort_t*)(ws + 428032);
    ushort_t* W1lo = (ushort_t*)(ws + 436224);
    ushort_t* W2hi = (ushort_t*)(ws + 444416);
    ushort_t* W2lo = (ushort_t*)(ws + 477184);
    ushort_t* W3hi = (ushort_t*)(ws + 509952);
    ushort_t* W3lo = (ushort_t*)(ws + 518144);
    ushort_t* Bb = (ushort_t*)(ws + 526336);    // xl bf16
    float* Cb = ws + 3086336;                   // xr fp32
    float* D  = ws + 8206336;                   // pre-norm GAT out

    const int TB = 256;
    const int MBm = (NN + 63)/64;    // 313
    const int NCH = 32;

    // 1: weight prep + cursor zeroing
    k_wprep_all<<<gridFor(NN, TB), TB, 0, stream>>>(W1l, W1r, W2l, W2r, W3l, W3r,
        W1hi, W1lo, W2hi, W2lo, W3hi, W3lo, cursor);
    // 2: degree count + graph bounds + gn-partial zero
    k_degbounds<<<gridFor(EE, TB), TB, 0, stream>>>(edst, cursor, batch, gstart, gend, gsumP);
    // 3: scan (int4-vectorized; re-zeroes cursor)
    k_scan<<<1, 1024, 0, stream>>>(cursor, indptr);
    // 4: gemm1 + scatter fused
    {
        int nGemm = MBm*4;
        int nScat = gridFor(EE, TB);
        k_gemm1_scatter<<<nGemm + nScat, 256, 0, stream>>>(x, W1hi, W1lo, b1l, b1r,
            Bb, Cb, esrc, edst, indptr, cursor, srclist, nGemm, MBm);
    }

    // ---- layer 1 rest ----
    k_gat_w<4, false><<<NN/4, 256, 0, stream>>>(indptr, srclist, Bb, Cb, att1, bias1, D);
    k_gn_partial<256><<<dim3(GG, NCH), 256, 0, stream>>>(D, gstart, gend, gsumP, gsqP);
    k_gn_finalize<<<gridFor(GG*256, TB), TB, 0, stream>>>(gsumP, gsqP, gstart, gend, g1m, gmu, ginv, 256);

    // ---- layer 2 ----
    k_gemm_mfma<true><<<dim3(MBm, 2), 256, 0, stream>>>(D, W2hi, W2lo, b2l, b2r,
        gmu, ginv, g1w, g1b, batch, Bb, Cb, 256, 256, 128);
    k_gat_w<2, false><<<NN/4, 256, 0, stream>>>(indptr, srclist, Bb, Cb, att2, bias2, D);
    k_gn_partial<128><<<dim3(GG, NCH), 128, 0, stream>>>(D, gstart, gend, gsumP, gsqP);
    k_gn_finalize<<<gridFor(GG*128, TB), TB, 0, stream>>>(gsumP, gsqP, gstart, gend, g2m, gmu, ginv, 128);

    // ---- layer 3 ----
    k_gemm_mfma<true><<<dim3(MBm, 1), 256, 0, stream>>>(D, W3hi, W3lo, b3l, b3r,
        gmu, ginv, g2w, g2b, batch, Bb, Cb, 128, 128, 64);
    k_gat_w<1, true><<<NN/4, 256, 0, stream>>>(indptr, srclist, Bb, Cb, att3, bias3, D);

    // ---- fused tail ----
    float* outLog  = (float*)d_out;
    float* outFeat = outLog + GG*4;
    k_tail<<<GG, 64, 0, stream>>>(D, gstart, gend, g3m, g3w, g3b, lin_w, lin_b, outLog, outFeat);
}

// Round 14
// 318.464 us; speedup vs baseline: 1.2057x; 1.0184x over previous
//
#include <hip/hip_runtime.h>
#include <math.h>

#define NN 20000
#define EE 320000
#define GG 64
#define HH 8
#define EPSV 1e-5f

static inline unsigned int gridFor(long n, int b){ return (unsigned int)((n + b - 1)/b); }

typedef __attribute__((ext_vector_type(8))) short short8;
typedef __attribute__((ext_vector_type(4))) float f32x4;
typedef unsigned short ushort_t;

// ---------------- bf16 helpers ----------------
__device__ __forceinline__ float asf(unsigned int u){
    union{unsigned int i; float f;} c; c.i = u; return c.f;
}
__device__ __forceinline__ ushort_t f2bf(float x){   // RNE
    unsigned u = __float_as_uint(x);
    unsigned r = u + 0x7FFFu + ((u >> 16) & 1u);
    return (ushort_t)(r >> 16);
}
__device__ __forceinline__ unsigned packbf(float a, float b){
    return (unsigned)f2bf(a) | ((unsigned)f2bf(b) << 16);
}
__device__ __forceinline__ void split_bf16(float x, short& hi, short& lo){
    unsigned u = __float_as_uint(x);
    unsigned r = u + 0x7FFFu + ((u >> 16) & 1u);
    hi = (short)(r >> 16);
    float hf = asf(((unsigned)(unsigned short)hi) << 16);
    float res = x - hf;
    unsigned u2 = __float_as_uint(res);
    unsigned r2 = u2 + 0x7FFFu + ((u2 >> 16) & 1u);
    lo = (short)(r2 >> 16);
}

// ---------------- weight prep (all 3 layers) + cursor zeroing ----------------
__device__ __forceinline__ void wprep_one(const float* Wl, const float* Wr,
                                          ushort_t* Whi, ushort_t* Wlo,
                                          int K, int Kp, int HC, int t){
    int octs = Kp >> 3;
    int n = t / octs, ko = t - n*octs;
    int kb = ko*8;
    const float* W = (n < HC) ? (Wl + n) : (Wr + (n - HC));
    short hi[8], lo[8];
    #pragma unroll
    for (int j = 0; j < 8; ++j){
        int k = kb + j;
        float v = (k < K) ? W[(long)k*HC] : 0.f;
        split_bf16(v, hi[j], lo[j]);
    }
    long base = (((long)(n>>4)*(Kp>>5) + (kb>>5))*64 + (n&15) + 16*((kb>>3)&3))*8;
    *(short8*)&Whi[base] = *(short8*)hi;
    *(short8*)&Wlo[base] = *(short8*)lo;
}

#define WP1 2048
#define WP2 8192
#define WP3 2048

__global__ void k_wprep_all(const float* __restrict__ W1l, const float* __restrict__ W1r,
                            const float* __restrict__ W2l, const float* __restrict__ W2r,
                            const float* __restrict__ W3l, const float* __restrict__ W3r,
                            ushort_t* __restrict__ W1hi, ushort_t* __restrict__ W1lo,
                            ushort_t* __restrict__ W2hi, ushort_t* __restrict__ W2lo,
                            ushort_t* __restrict__ W3hi, ushort_t* __restrict__ W3lo,
                            int* __restrict__ cursor){
    int t = blockIdx.x*blockDim.x + threadIdx.x;
    if (t < NN) cursor[t] = 0;
    if (t < WP1) wprep_one(W1l, W1r, W1hi, W1lo, 19, 32, 256, t);
    else if (t < WP1+WP2) wprep_one(W2l, W2r, W2hi, W2lo, 256, 256, 128, t-WP1);
    else if (t < WP1+WP2+WP3) wprep_one(W3l, W3r, W3hi, W3lo, 128, 128, 64, t-WP1-WP2);
}

// ---------------- degree count + graph bounds + gn-partial zeroing ----------------
__global__ void k_degbounds(const int* __restrict__ edst, int* __restrict__ deg,
                            const int* __restrict__ batch,
                            int* __restrict__ gstart, int* __restrict__ gend,
                            float* __restrict__ gz){
    int e = blockIdx.x*blockDim.x + threadIdx.x;
    if (e < EE) atomicAdd(&deg[edst[e]], 1);
    if (e < NN){
        int b = batch[e];
        if (e == 0 || batch[e-1] != b) gstart[b] = e;
        if (e == NN-1 || batch[e+1] != b) gend[b] = e+1;
    }
    if (e < 2*GG*256) gz[e] = 0.f;
}

// ---------------- exclusive scan, int4-vectorized (NN = 1000*20 exactly) ----------------
__global__ void k_scan(int* __restrict__ deg, int* __restrict__ indptr){
    __shared__ int partial[1024];
    int t = threadIdx.x;
    int vals[20];
    int sum = 0;
    if (t < 1000){
        int4 buf[5];
        const int4* p = (const int4*)(deg + t*20);
        #pragma unroll
        for (int i = 0; i < 5; ++i) buf[i] = p[i];
        const int* bv = (const int*)buf;
        #pragma unroll
        for (int i = 0; i < 20; ++i){ vals[i] = sum; sum += bv[i]; }
        int4 z = make_int4(0,0,0,0);
        int4* pz = (int4*)(deg + t*20);
        #pragma unroll
        for (int i = 0; i < 5; ++i) pz[i] = z;
    }
    partial[t] = sum;
    __syncthreads();
    for (int off = 1; off < 1024; off <<= 1){
        int v = (t >= off) ? partial[t-off] : 0;
        __syncthreads();
        partial[t] += v;
        __syncthreads();
    }
    int prefix = (t > 0) ? partial[t-1] : 0;
    if (t < 1000){
        int out[20];
        #pragma unroll
        for (int i = 0; i < 20; ++i) out[i] = prefix + vals[i];
        int4* q = (int4*)(indptr + t*20);
        #pragma unroll
        for (int i = 0; i < 5; ++i) q[i] = ((const int4*)out)[i];
    }
    if (t == 1023) indptr[NN] = prefix;
}

// ---------------- bf16-split MFMA dual linear body ----------------
// NORM=false: A from fp32 hf. NORM=true: A from bf16 hb with fused GraphNorm+ReLU.
template<bool NORM>
__device__ __forceinline__ void gemm_body(
    const float* __restrict__ hf, const ushort_t* __restrict__ hb,
    const ushort_t* __restrict__ Whi, const ushort_t* __restrict__ Wlo,
    const float* __restrict__ bl, const float* __restrict__ br,
    const float* __restrict__ gmu, const float* __restrict__ ginv,
    const float* __restrict__ nw, const float* __restrict__ nb,
    const int* __restrict__ batch,
    ushort_t* __restrict__ xlb, float* __restrict__ xr,
    int K, int Kp, int HC, int bm, int bn){
    __shared__ short Ahi[2][64*32], Alo[2][64*32];
    const int tid  = threadIdx.x;
    const int lane = tid & 63;
    const int wave = tid >> 6;
    const int m0   = bm * 64;
    const int n0   = bn * 128;
    const int wr   = (wave & 1) * 32;
    const int wcg  = (wave >> 1) * 64;
    const int kblocks = Kp >> 5;

    const int srow = tid >> 2;
    const int soct = tid & 3;

    f32x4 acc[2][4] = {};

    for (int kb = 0; kb < kblocks; ++kb){
        int p = kb & 1;
        int k0 = kb*32;
        {
            int gm = m0 + srow;
            int kbase = k0 + soct*8;
            float v[8];
            if (NORM){
                if (gm < NN){
                    short8 raw = *(const short8*)(hb + (long)gm*K + kbase);
                    int g = batch[gm];
                    const float* mu = gmu + (long)g*K;
                    const float* iv = ginv + (long)g*K;
                    #pragma unroll
                    for (int j = 0; j < 8; ++j){
                        int c = kbase + j;
                        float xv = asf(((unsigned)(unsigned short)raw[j]) << 16);
                        float t = (xv - mu[c]) * iv[c] * nw[c] + nb[c];
                        v[j] = fmaxf(t, 0.f);
                    }
                } else {
                    #pragma unroll
                    for (int j = 0; j < 8; ++j) v[j] = 0.f;
                }
            } else {
                const float* src = hf + (long)gm*K + kbase;
                if (gm < NN && kbase + 8 <= K){
                    float4 t0 = *(const float4*)src;
                    float4 t1 = *(const float4*)(src+4);
                    v[0]=t0.x; v[1]=t0.y; v[2]=t0.z; v[3]=t0.w;
                    v[4]=t1.x; v[5]=t1.y; v[6]=t1.z; v[7]=t1.w;
                } else {
                    #pragma unroll
                    for (int j = 0; j < 8; ++j)
                        v[j] = (gm < NN && kbase + j < K) ? src[j] : 0.f;
                }
            }
            short hi[8], lo[8];
            #pragma unroll
            for (int j = 0; j < 8; ++j) split_bf16(v[j], hi[j], lo[j]);
            long off = ((long)(srow>>4)*64 + (srow&15) + 16*soct)*8;
            *(short8*)&Ahi[p][off] = *(short8*)hi;
            *(short8*)&Alo[p][off] = *(short8*)lo;
        }
        __syncthreads();

        int rb0 = wr >> 4;
        short8 ah0 = *(short8*)&Ahi[p][((rb0  )*64 + lane)*8];
        short8 ah1 = *(short8*)&Ahi[p][((rb0+1)*64 + lane)*8];
        short8 al0 = *(short8*)&Alo[p][((rb0  )*64 + lane)*8];
        short8 al1 = *(short8*)&Alo[p][((rb0+1)*64 + lane)*8];

        short8 bh[4], bl_[4];
        #pragma unroll
        for (int j = 0; j < 4; ++j){
            int n = n0 + wcg + j*16;
            long bbase = (((long)(n>>4)*kblocks + kb)*64 + lane)*8;
            bh[j]  = *(const short8*)&Whi[bbase];
            bl_[j] = *(const short8*)&Wlo[bbase];
        }

        #pragma unroll
        for (int j = 0; j < 4; ++j){
            acc[0][j] = __builtin_amdgcn_mfma_f32_16x16x32_bf16(al0, bh[j],  acc[0][j], 0,0,0);
            acc[0][j] = __builtin_amdgcn_mfma_f32_16x16x32_bf16(ah0, bl_[j], acc[0][j], 0,0,0);
            acc[0][j] = __builtin_amdgcn_mfma_f32_16x16x32_bf16(ah0, bh[j],  acc[0][j], 0,0,0);
            acc[1][j] = __builtin_amdgcn_mfma_f32_16x16x32_bf16(al1, bh[j],  acc[1][j], 0,0,0);
            acc[1][j] = __builtin_amdgcn_mfma_f32_16x16x32_bf16(ah1, bl_[j], acc[1][j], 0,0,0);
            acc[1][j] = __builtin_amdgcn_mfma_f32_16x16x32_bf16(ah1, bh[j],  acc[1][j], 0,0,0);
        }
    }

    #pragma unroll
    for (int i = 0; i < 2; ++i){
        int row0 = m0 + wr + i*16 + (lane >> 4)*4;
        #pragma unroll
        for (int j = 0; j < 4; ++j){
            int n = n0 + wcg + j*16 + (lane & 15);
            float bb = (n < HC) ? bl[n] : br[n - HC];
            #pragma unroll
            for (int r = 0; r < 4; ++r){
                int gm = row0 + r;
                if (gm >= NN) continue;
                float v = acc[i][j][r] + bb;
                if (n < HC) xlb[(long)gm*HC + n] = f2bf(v);
                else        xr[(long)gm*HC + (n - HC)] = v;
            }
        }
    }
}

template<bool NORM>
__global__ __launch_bounds__(256)
void k_gemm_mfma(const float* __restrict__ hf, const ushort_t* __restrict__ hb,
                 const ushort_t* __restrict__ Whi, const ushort_t* __restrict__ Wlo,
                 const float* __restrict__ bl, const float* __restrict__ br,
                 const float* __restrict__ gmu, const float* __restrict__ ginv,
                 const float* __restrict__ nw, const float* __restrict__ nb,
                 const int* __restrict__ batch,
                 ushort_t* __restrict__ xlb, float* __restrict__ xr,
                 int K, int Kp, int HC){
    gemm_body<NORM>(hf, hb, Whi, Wlo, bl, br, gmu, ginv, nw, nb, batch, xlb, xr,
                    K, Kp, HC, blockIdx.x, blockIdx.y);
}

// gemm1 + scatter in one dispatch (independent work, concurrent pipes)
__global__ __launch_bounds__(256)
void k_gemm1_scatter(const float* __restrict__ x,
                     const ushort_t* __restrict__ Whi, const ushort_t* __restrict__ Wlo,
                     const float* __restrict__ bl, const float* __restrict__ br,
                     ushort_t* __restrict__ xlb, float* __restrict__ xr,
                     const int* __restrict__ esrc, const int* __restrict__ edst,
                     const int* __restrict__ indptr, int* __restrict__ cursor,
                     int* __restrict__ srclist, int nGemm, int mb){
    if ((int)blockIdx.x < nGemm){
        gemm_body<false>(x, nullptr, Whi, Wlo, bl, br, nullptr, nullptr, nullptr, nullptr,
                         nullptr, xlb, xr, 19, 32, 256, blockIdx.x % mb, blockIdx.x / mb);
    } else {
        int e = (blockIdx.x - nGemm)*256 + threadIdx.x;
        if (e < EE){
            int d = edst[e];
            int pos = atomicAdd(&cursor[d], 1);
            srclist[indptr[d] + pos] = esrc[e];
        }
    }
}

// ---------------- fused GATv2, wave-per-node, bf16 gather, bf16 output ----------------
template<int VEC> struct VT;
template<> struct VT<1>{ using T = float;  };
template<> struct VT<2>{ using T = float2; };
template<> struct VT<4>{ using T = float4; };

template<int VEC> struct BF;
template<> struct BF<1>{
    static __device__ __forceinline__ float load(const ushort_t* p){
        return asf(((unsigned)*p) << 16);
    }
};
template<> struct BF<2>{
    static __device__ __forceinline__ float2 load(const ushort_t* p){
        unsigned u = *(const unsigned*)p;
        return make_float2(asf(u << 16), asf(u & 0xFFFF0000u));
    }
};
template<> struct BF<4>{
    static __device__ __forceinline__ float4 load(const ushort_t* p){
        uint2 u = *(const uint2*)p;
        return make_float4(asf(u.x << 16), asf(u.x & 0xFFFF0000u),
                           asf(u.y << 16), asf(u.y & 0xFFFF0000u));
    }
};

__device__ __forceinline__ float lrelu(float z){ return z > 0.f ? z : 0.2f*z; }

__device__ __forceinline__ float edot(float xv, float xr, float at){
    return lrelu(xv + xr) * at;
}
__device__ __forceinline__ float edot(float2 xv, float2 xr, float2 at){
    return lrelu(xv.x+xr.x)*at.x + lrelu(xv.y+xr.y)*at.y;
}
__device__ __forceinline__ float edot(float4 xv, float4 xr, float4 at){
    return lrelu(xv.x+xr.x)*at.x + lrelu(xv.y+xr.y)*at.y
         + lrelu(xv.z+xr.z)*at.z + lrelu(xv.w+xr.w)*at.w;
}
__device__ __forceinline__ void efma(float& o, float p, float xv){ o = fmaf(p,xv,o); }
__device__ __forceinline__ void efma(float2& o, float p, float2 xv){
    o.x = fmaf(p,xv.x,o.x); o.y = fmaf(p,xv.y,o.y);
}
__device__ __forceinline__ void efma(float4& o, float p, float4 xv){
    o.x = fmaf(p,xv.x,o.x); o.y = fmaf(p,xv.y,o.y);
    o.z = fmaf(p,xv.z,o.z); o.w = fmaf(p,xv.w,o.w);
}
__device__ __forceinline__ float escale(float o, float s, float b){ return fmaf(o,s,b); }
__device__ __forceinline__ float2 escale(float2 o, float s, float2 b){
    return make_float2(fmaf(o.x,s,b.x), fmaf(o.y,s,b.y));
}
__device__ __forceinline__ float4 escale(float4 o, float s, float4 b){
    return make_float4(fmaf(o.x,s,b.x), fmaf(o.y,s,b.y), fmaf(o.z,s,b.z), fmaf(o.w,s,b.w));
}

__device__ __forceinline__ float red8(float v){
    v += __shfl_xor(v, 1);
    v += __shfl_xor(v, 2);
    v += __shfl_xor(v, 4);
    return v;
}

template<int VEC, bool MEAN>
__global__ __launch_bounds__(256)
void k_gat_w(const int* __restrict__ indptr, const int* __restrict__ srclist,
             const ushort_t* __restrict__ xlb, const float* __restrict__ xr,
             const float* __restrict__ att, const float* __restrict__ bias,
             ushort_t* __restrict__ valb){
    using V = typename VT<VEC>::T;
    constexpr int HC = 64*VEC;
    const int lane = threadIdx.x & 63;
    const int d = blockIdx.x*4 + (threadIdx.x >> 6);
    const int co = lane*VEC;

    V xrd = *(const V*)&xr[(long)d*HC + co];
    V at  = *(const V*)&att[co];
    V xls = BF<VEC>::load(xlb + (long)d*HC + co);

    float m0 = red8(edot(xls, xrd, at));
    float l = 1.0f;
    V o = xls;

    int j = indptr[d], end = indptr[d+1];   // wave-uniform
    for (; j + 8 <= end; j += 8){
        int s0 = srclist[j+0], s1 = srclist[j+1], s2 = srclist[j+2], s3 = srclist[j+3];
        int s4 = srclist[j+4], s5 = srclist[j+5], s6 = srclist[j+6], s7 = srclist[j+7];
        V x0 = BF<VEC>::load(xlb + (long)s0*HC + co);
        V x1 = BF<VEC>::load(xlb + (long)s1*HC + co);
        V x2 = BF<VEC>::load(xlb + (long)s2*HC + co);
        V x3 = BF<VEC>::load(xlb + (long)s3*HC + co);
        V x4 = BF<VEC>::load(xlb + (long)s4*HC + co);
        V x5 = BF<VEC>::load(xlb + (long)s5*HC + co);
        V x6 = BF<VEC>::load(xlb + (long)s6*HC + co);
        V x7 = BF<VEC>::load(xlb + (long)s7*HC + co);
        float a0 = red8(edot(x0, xrd, at));
        float a1 = red8(edot(x1, xrd, at));
        float a2 = red8(edot(x2, xrd, at));
        float a3 = red8(edot(x3, xrd, at));
        float a4 = red8(edot(x4, xrd, at));
        float a5 = red8(edot(x5, xrd, at));
        float a6 = red8(edot(x6, xrd, at));
        float a7 = red8(edot(x7, xrd, at));
        float p0 = __expf(a0 - m0), p1 = __expf(a1 - m0);
        float p2 = __expf(a2 - m0), p3 = __expf(a3 - m0);
        float p4 = __expf(a4 - m0), p5 = __expf(a5 - m0);
        float p6 = __expf(a6 - m0), p7 = __expf(a7 - m0);
        l += ((p0+p1)+(p2+p3)) + ((p4+p5)+(p6+p7));
        efma(o, p0, x0); efma(o, p1, x1); efma(o, p2, x2); efma(o, p3, x3);
        efma(o, p4, x4); efma(o, p5, x5); efma(o, p6, x6); efma(o, p7, x7);
    }
    for (; j < end; j += 4){
        int m = end - j;
        int s0 = srclist[j];
        int s1 = (m > 1) ? srclist[j+1] : s0;
        int s2 = (m > 2) ? srclist[j+2] : s0;
        int s3 = (m > 3) ? srclist[j+3] : s0;
        V x0 = BF<VEC>::load(xlb + (long)s0*HC + co);
        V x1 = BF<VEC>::load(xlb + (long)s1*HC + co);
        V x2 = BF<VEC>::load(xlb + (long)s2*HC + co);
        V x3 = BF<VEC>::load(xlb + (long)s3*HC + co);
        float a0 = red8(edot(x0, xrd, at));
        float a1 = red8(edot(x1, xrd, at));
        float a2 = red8(edot(x2, xrd, at));
        float a3 = red8(edot(x3, xrd, at));
        float p0 = __expf(a0 - m0);
        float p1 = __expf(a1 - m0);
        float p2 = __expf(a2 - m0);
        float p3 = __expf(a3 - m0);
        l += p0; efma(o, p0, x0);
        if (m > 1){ l += p1; efma(o, p1, x1); }
        if (m > 2){ l += p2; efma(o, p2, x2); }
        if (m > 3){ l += p3; efma(o, p3, x3); }
    }
    float invl = 1.0f / l;
    if (!MEAN){
        if (VEC == 4){
            float4 r = escale(*(float4*)&o, invl, *(const float4*)&bias[co]);
            *(uint2*)&valb[(long)d*HC + co] = make_uint2(packbf(r.x, r.y), packbf(r.z, r.w));
        } else {
            float2 r = escale(*(float2*)&o, invl, *(const float2*)&bias[co]);
            *(unsigned*)&valb[(long)d*HC + co] = packbf(r.x, r.y);
        }
    } else {
        float r = ((float&)o) * invl;
        r += __shfl_xor(r, 8);
        r += __shfl_xor(r, 16);
        r += __shfl_xor(r, 32);
        if (lane < 8) valb[(long)d*8 + lane] = f2bf(r*0.125f + bias[lane]);
    }
}

// ---------------- GraphNorm stats: chunked partials + finalize (self-zeroing) ----------------
template<int F>
__global__ void k_gn_partial(const ushort_t* __restrict__ val,
                             const int* __restrict__ gstart, const int* __restrict__ gend,
                             float* __restrict__ gsum, float* __restrict__ gsq){
    int g = blockIdx.x, ch = blockIdx.y, nch = gridDim.y;
    int c = threadIdx.x;
    int s = gstart[g], e = gend[g];
    float sum = 0.f, sq = 0.f;
    for (int i = s + ch; i < e; i += nch){
        float v = asf(((unsigned)val[(long)i*F + c]) << 16);
        sum += v; sq += v*v;
    }
    if (sum != 0.f || sq != 0.f){
        atomicAdd(&gsum[g*F + c], sum);
        atomicAdd(&gsq[g*F + c], sq);
    }
}

__global__ void k_gn_finalize(float* __restrict__ gsum, float* __restrict__ gsq,
                              const int* __restrict__ gstart, const int* __restrict__ gend,
                              const float* __restrict__ ms,
                              float* __restrict__ gmu, float* __restrict__ ginv, int F){
    int idx = blockIdx.x*blockDim.x + threadIdx.x;
    if (idx >= GG*F) return;
    int g = idx / F, c = idx - g*F;
    int cnti = gend[g] - gstart[g];
    float cn = cnti > 0 ? (float)cnti : 1.f;
    float mean = gsum[idx] / cn;
    float mu = mean * ms[c];
    float var = gsq[idx]/cn - 2.f*mu*mean + mu*mu;
    gmu[idx]  = mu;
    ginv[idx] = rsqrtf(var + EPSV);
    gsum[idx] = 0.f;
    gsq[idx]  = 0.f;
}

// ---------------- fused tail: layer-3 GraphNorm stats + norm+relu pool + logits ----------------
__global__ void k_tail(const ushort_t* __restrict__ D,
                       const int* __restrict__ gstart, const int* __restrict__ gend,
                       const float* __restrict__ ms, const float* __restrict__ w,
                       const float* __restrict__ b,
                       const float* __restrict__ lw, const float* __restrict__ lb,
                       float* __restrict__ outLog, float* __restrict__ outFeat){
    int g = blockIdx.x;
    int t = threadIdx.x;
    int c = t & 7, r = t >> 3;
    int s = gstart[g], e = gend[g];
    int cnti = e - s;
    float cn = cnti > 0 ? (float)cnti : 1.f;

    float sum = 0.f, sq = 0.f;
    for (int i = s + r; i < e; i += 8){
        float v = asf(((unsigned)D[(long)i*8 + c]) << 16);
        sum += v; sq += v*v;
    }
    #pragma unroll
    for (int mask = 8; mask < 64; mask <<= 1){
        sum += __shfl_xor(sum, mask, 64);
        sq  += __shfl_xor(sq,  mask, 64);
    }
    float mean = sum / cn;
    float mu = mean * ms[c];
    float var = sq/cn - 2.f*mu*mean + mu*mu;
    float iv = rsqrtf(var + EPSV);
    float wc = w[c], bc = b[c];

    float psum = 0.f;
    for (int i = s + r; i < e; i += 8){
        float v = (asf(((unsigned)D[(long)i*8 + c]) << 16) - mu) * iv * wc + bc;
        psum += fmaxf(v, 0.f);
    }
    #pragma unroll
    for (int mask = 8; mask < 64; mask <<= 1)
        psum += __shfl_xor(psum, mask, 64);
    float feat = psum / cn;

    if (t < 8) outFeat[g*8 + t] = feat;

    float a = 0.f;
    int jj = t;
    if (t < 4) a = lb[jj];
    #pragma unroll
    for (int cc = 0; cc < 8; ++cc){
        float fc = __shfl(feat, cc, 64);
        if (t < 4) a += fc * lw[cc*4 + jj];
    }
    if (t < 4) outLog[g*4 + jj] = a;
}

extern "C" void kernel_launch(void* const* d_in, const int* in_sizes, int n_in,
                              void* d_out, int out_size, void* d_ws, size_t ws_size,
                              hipStream_t stream) {
    const float* x     = (const float*)d_in[0];
    const int*   ei    = (const int*)  d_in[1];
    const int*   batch = (const int*)  d_in[2];
    const float* W1l = (const float*)d_in[3];  const float* b1l = (const float*)d_in[4];
    const float* W1r = (const float*)d_in[5];  const float* b1r = (const float*)d_in[6];
    const float* att1= (const float*)d_in[7];  const float* bias1=(const float*)d_in[8];
    const float* g1w = (const float*)d_in[9];  const float* g1b = (const float*)d_in[10];
    const float* g1m = (const float*)d_in[11];
    const float* W2l = (const float*)d_in[12]; const float* b2l = (const float*)d_in[13];
    const float* W2r = (const float*)d_in[14]; const float* b2r = (const float*)d_in[15];
    const float* att2= (const float*)d_in[16]; const float* bias2=(const float*)d_in[17];
    const float* g2w = (const float*)d_in[18]; const float* g2b = (const float*)d_in[19];
    const float* g2m = (const float*)d_in[20];
    const float* W3l = (const float*)d_in[21]; const float* b3l = (const float*)d_in[22];
    const float* W3r = (const float*)d_in[23]; const float* b3r = (const float*)d_in[24];
    const float* att3= (const float*)d_in[25]; const float* bias3=(const float*)d_in[26];
    const float* g3w = (const float*)d_in[27]; const float* g3b = (const float*)d_in[28];
    const float* g3m = (const float*)d_in[29];
    const float* lin_w=(const float*)d_in[30]; const float* lin_b=(const float*)d_in[31];

    const int* esrc = ei;
    const int* edst = ei + EE;

    // ---- workspace arena (units of 4B) ----
    float* ws = (float*)d_ws;
    int*   cursor  = (int*)(ws + 0);
    int*   indptr  = (int*)(ws + 20480);
    int*   srclist = (int*)(ws + 40960);
    int*   gstart  = (int*)(ws + 361472);
    int*   gend    = (int*)(ws + 361984);
    float* gmu     = ws + 362496;
    float* ginv    = ws + 378880;
    float* gsumP   = ws + 395264;
    float* gsqP    = ws + 411648;
    ushort_t* W1hi = (ushort_t*)(ws + 428032);
    ushort_t* W1lo = (ushort_t*)(ws + 436224);
    ushort_t* W2hi = (ushort_t*)(ws + 444416);
    ushort_t* W2lo = (ushort_t*)(ws + 477184);
    ushort_t* W3hi = (ushort_t*)(ws + 509952);
    ushort_t* W3lo = (ushort_t*)(ws + 518144);
    ushort_t* Bb = (ushort_t*)(ws + 526336);    // xl bf16: 2,560,000 words
    float* Cb = ws + 3086336;                   // xr fp32: 5,120,000 words
    ushort_t* Db = (ushort_t*)(ws + 8206336);   // pre-norm GAT out, bf16: 2,560,000 words

    const int TB = 256;
    const int MBm = (NN + 63)/64;    // 313
    const int NCH = 32;

    // 1: weight prep + cursor zeroing
    k_wprep_all<<<gridFor(NN, TB), TB, 0, stream>>>(W1l, W1r, W2l, W2r, W3l, W3r,
        W1hi, W1lo, W2hi, W2lo, W3hi, W3lo, cursor);
    // 2: degree count + graph bounds + gn-partial zero
    k_degbounds<<<gridFor(EE, TB), TB, 0, stream>>>(edst, cursor, batch, gstart, gend, gsumP);
    // 3: scan (int4-vectorized; re-zeroes cursor)
    k_scan<<<1, 1024, 0, stream>>>(cursor, indptr);
    // 4: gemm1 + scatter fused
    {
        int nGemm = MBm*4;
        int nScat = gridFor(EE, TB);
        k_gemm1_scatter<<<nGemm + nScat, 256, 0, stream>>>(x, W1hi, W1lo, b1l, b1r,
            Bb, Cb, esrc, edst, indptr, cursor, srclist, nGemm, MBm);
    }

    // ---- layer 1 rest ----
    k_gat_w<4, false><<<NN/4, 256, 0, stream>>>(indptr, srclist, Bb, Cb, att1, bias1, Db);
    k_gn_partial<256><<<dim3(GG, NCH), 256, 0, stream>>>(Db, gstart, gend, gsumP, gsqP);
    k_gn_finalize<<<gridFor(GG*256, TB), TB, 0, stream>>>(gsumP, gsqP, gstart, gend, g1m, gmu, ginv, 256);

    // ---- layer 2 ----
    k_gemm_mfma<true><<<dim3(MBm, 2), 256, 0, stream>>>(nullptr, Db, W2hi, W2lo, b2l, b2r,
        gmu, ginv, g1w, g1b, batch, Bb, Cb, 256, 256, 128);
    k_gat_w<2, false><<<NN/4, 256, 0, stream>>>(indptr, srclist, Bb, Cb, att2, bias2, Db);
    k_gn_partial<128><<<dim3(GG, NCH), 128, 0, stream>>>(Db, gstart, gend, gsumP, gsqP);
    k_gn_finalize<<<gridFor(GG*128, TB), TB, 0, stream>>>(gsumP, gsqP, gstart, gend, g2m, gmu, ginv, 128);

    // ---- layer 3 ----
    k_gemm_mfma<true><<<dim3(MBm, 1), 256, 0, stream>>>(nullptr, Db, W3hi, W3lo, b3l, b3r,
        gmu, ginv, g2w, g2b, batch, Bb, Cb, 128, 128, 64);
    k_gat_w<1, true><<<NN/4, 256, 0, stream>>>(indptr, srclist, Bb, Cb, att3, bias3, Db);

    // ---- fused tail ----
    float* outLog  = (float*)d_out;
    float* outFeat = outLog + GG*4;
    k_tail<<<GG, 64, 0, stream>>>(Db, gstart, gend, g3m, g3w, g3b, lin_w, lin_b, outLog, outFeat);
}